// Round 13
// baseline (50.663 us; speedup 1.0000x reference)
//
#include <hip/hip_runtime.h>
#include <hip/hip_bf16.h>

#define EPS 1e-12f
// Features stored pre-scaled by sqrt(C_EXP), C_EXP=(1/0.07)*log2(e):
// MFMA output is exp2-ready: exp(sim/T) == exp2(fs_i . fs_j).
#define SQRT_C_EXP 4.53981597f
#define M_LN2F 0.69314718056f
#define NUM_CLASSES 16
#define CS_BLOCKS 128

#define BM 128          // rows per denom block
#define BN 64           // cols per chunk
#define KD 128          // feature dim
#define NCHUNK 16       // col chunks per colgroup (1024 cols)
#define NCOLG 8
#define NPART 32        // colgroups(8) * wc(4)

typedef __attribute__((ext_vector_type(4))) float f32x4;
typedef __attribute__((ext_vector_type(8))) short bf16x8;

__device__ __forceinline__ float bf2f(ushort u) {
    unsigned int x = ((unsigned int)u) << 16;
    return __uint_as_float(x);
}

// Direct global->LDS 16B/lane DMA. LDS dest must be linear in lane order;
// swizzle is applied to the GLOBAL source address instead (involution).
__device__ __forceinline__ void gload16(const void* g, void* l) {
    __builtin_amdgcn_global_load_lds(
        (const __attribute__((address_space(1))) void*)g,
        (__attribute__((address_space(3))) void*)l, 16, 0, 0);
}

// Swizzled LDS fragment address: element (r, slot) of a [rows][128] bf16 tile,
// slot = 16B chunk within the 256B row. Swizzle: slot ^= (r&7).
__device__ __forceinline__ const bf16x8* lds_frag(const ushort* base, int r, int slot) {
    int sw = slot ^ (r & 7);
    return reinterpret_cast<const bf16x8*>(
        reinterpret_cast<const char*>(base) + r * 256 + sw * 16);
}

// ---------------- Kernel A: L2-normalize rows -> bf16 (pre-scaled) ----------
// One wave per row; D=128 = 64 lanes x float2. sq[r] = ||fs_bf16||^2 (scaled).
// Block 0 also zeroes g/cntf (stream order makes this visible to classsum).
__global__ void normalize_kernel(const float* __restrict__ feat,
                                 ushort* __restrict__ fb,
                                 float* __restrict__ sq,
                                 float* __restrict__ gz,   // g..cntf, 2064 floats
                                 int N) {
    if (blockIdx.x == 0) {
        for (int i = threadIdx.x; i < NUM_CLASSES * KD + NUM_CLASSES; i += 256)
            gz[i] = 0.f;
    }
    int r    = (blockIdx.x * blockDim.x + threadIdx.x) >> 6;
    int lane = threadIdx.x & 63;
    if (r >= N) return;
    const float2 v = *reinterpret_cast<const float2*>(feat + (size_t)r * KD + lane * 2);
    float s = v.x * v.x + v.y * v.y;
    #pragma unroll
    for (int off = 1; off < 64; off <<= 1) s += __shfl_xor(s, off);
    const float scale = SQRT_C_EXP / fmaxf(sqrtf(s), EPS);

    __hip_bfloat16 h0 = __float2bfloat16(v.x * scale);
    __hip_bfloat16 h1 = __float2bfloat16(v.y * scale);
    ushort u0 = *reinterpret_cast<ushort*>(&h0);
    ushort u1 = *reinterpret_cast<ushort*>(&h1);
    unsigned int pack = (unsigned int)u0 | ((unsigned int)u1 << 16);
    *reinterpret_cast<unsigned int*>(fb + (size_t)r * KD + lane * 2) = pack;

    float q0 = bf2f(u0), q1 = bf2f(u1);
    float q = q0 * q0 + q1 * q1;
    #pragma unroll
    for (int off = 1; off < 64; off <<= 1) q += __shfl_xor(q, off);
    if (lane == 0) sq[r] = q;                 // sq_s = C_EXP*||f||^2
}

// ---------------- Kernel A2: per-class feature sums + counts ----------------
// 128 blocks x 64 rows. Each thread owns LDS slot [half][class][col]:
// no atomics in the loop; one global atomicAdd per (class,col) per block.
__global__ __launch_bounds__(256) void classsum_kernel(
    const ushort* __restrict__ fb,
    const int* __restrict__ labels,
    float* __restrict__ g,
    float* __restrict__ cntf,
    int N) {
    __shared__ float lds[2][NUM_CLASSES][128];
    __shared__ float ldc[2][NUM_CLASSES];
    const int d    = threadIdx.x & 127;
    const int half = threadIdx.x >> 7;
    #pragma unroll
    for (int c = 0; c < NUM_CLASSES; c++) lds[half][c][d] = 0.f;
    if (d < NUM_CLASSES) ldc[half][d] = 0.f;
    __syncthreads();

    const int r0 = blockIdx.x * 64 + half * 32;
    for (int r = r0; r < r0 + 32; r++) {
        int lab = labels[r];
        lds[half][lab][d] += bf2f(fb[(size_t)r * KD + d]);
        if (d == 0) ldc[half][lab] += 1.f;
    }
    __syncthreads();

    for (int c = half; c < NUM_CLASSES; c += 2)
        atomicAdd(&g[c * KD + d], lds[0][c][d] + lds[1][c][d]);
    if (threadIdx.x < NUM_CLASSES)
        atomicAdd(&cntf[threadIdx.x], ldc[0][threadIdx.x] + ldc[1][threadIdx.x]);
}

// ---------------- Kernel B: denom partials, 2 blocks/CU, global_load_lds ----
// 512 blocks (grid 8 colgroups x 64 rowblocks), 512 threads = 8 waves (2x4),
// wave tile 64x16, A-frags in registers. LDS = A 32KB + B dbuf 2x16KB = 64KB
// -> 2 blocks/CU, 4 waves/SIMD. Staging via global_load_lds with the XOR
// swizzle pre-applied to the global source (LDS dest stays linear).
__global__ __launch_bounds__(512, 4) void supcon_denom(
    const ushort* __restrict__ fb,
    float* __restrict__ denom_part,
    int N) {

    __shared__ __align__(16) ushort As[BM * KD];        // 32 KB
    __shared__ __align__(16) ushort Bs[2][BN * KD];     // 2 x 16 KB

    const int tid  = threadIdx.x;
    const int lane = tid & 63;
    const int w    = tid >> 6;        // 0..7
    const int wr   = w >> 2;          // 0..1  (64-row half)
    const int wc   = w & 3;           // 0..3  (16-col quarter)
    const int r16  = lane & 15;
    const int g4   = lane >> 4;       // 0..3

    const int rowbase = blockIdx.y * BM;
    const int col0    = blockIdx.x * (BN * NCHUNK);

    // ---- stage A tile (32KB = 4 gloads) + B chunk 0 (16KB = 2 gloads) ----
    {
        const ushort* gA = fb + (size_t)rowbase * KD;
        #pragma unroll
        for (int i = 0; i < 4; i++) {
            int d = i * 512 + tid;                  // linear 16B-chunk index
            int s = d ^ ((d >> 4) & 7);             // pre-swizzled source
            gload16(gA + (size_t)s * 8, &As[d * 8]);
        }
        const ushort* gB = fb + (size_t)col0 * KD;
        #pragma unroll
        for (int i = 0; i < 2; i++) {
            int d = i * 512 + tid;
            int s = d ^ ((d >> 4) & 7);
            gload16(gB + (size_t)s * 8, &Bs[0][d * 8]);
        }
    }
    __syncthreads();

    // ---- A fragments for the whole block, read from LDS once ----
    bf16x8 a[4][4];                   // [ks][m], 64 VGPR, static indexing only
    #pragma unroll
    for (int ks = 0; ks < 4; ks++) {
        const int slot = ks * 4 + g4;
        #pragma unroll
        for (int m = 0; m < 4; m++)
            a[ks][m] = *lds_frag(As, wr * 64 + m * 16 + r16, slot);
    }

    float pd[4][4];                   // [m][i] per-row exp-sum partials
    #pragma unroll
    for (int m = 0; m < 4; m++)
        #pragma unroll
        for (int i = 0; i < 4; i++) pd[m][i] = 0.f;

    int cur = 0;
    for (int c = 0; c < NCHUNK; c++) {
        // issue next-chunk DMA into the other buffer (drained by the barrier)
        if (c + 1 < NCHUNK) {
            const ushort* gB = fb + (size_t)(col0 + (c + 1) * BN) * KD;
            ushort* dstb = Bs[cur ^ 1];
            #pragma unroll
            for (int i = 0; i < 2; i++) {
                int d = i * 512 + tid;
                int s = d ^ ((d >> 4) & 7);
                gload16(gB + (size_t)s * 8, &dstb[d * 8]);
            }
        }

        f32x4 acc[4];
        #pragma unroll
        for (int m = 0; m < 4; m++) acc[m] = f32x4{0.f, 0.f, 0.f, 0.f};

        const ushort* bbase = Bs[cur];
        #pragma unroll
        for (int ks = 0; ks < 4; ks++) {
            const int slot = ks * 4 + g4;
            bf16x8 bv = *lds_frag(bbase, wc * 16 + r16, slot);
            #pragma unroll
            for (int m = 0; m < 4; m++)
                acc[m] = __builtin_amdgcn_mfma_f32_16x16x32_bf16(a[ks][m], bv, acc[m], 0, 0, 0);
        }

        #pragma unroll
        for (int m = 0; m < 4; m++)
            #pragma unroll
            for (int i = 0; i < 4; i++)
                pd[m][i] += __builtin_amdgcn_exp2f(acc[m][i]);

        __syncthreads();
        cur ^= 1;
    }

    // reduce across the 16 lanes sharing the same rows, write partials
    #pragma unroll
    for (int off = 1; off < 16; off <<= 1)
        #pragma unroll
        for (int m = 0; m < 4; m++)
            #pragma unroll
            for (int i = 0; i < 4; i++)
                pd[m][i] += __shfl_xor(pd[m][i], off);

    if (r16 == 0) {
        const int part = blockIdx.x * 4 + wc;   // 0..31
        #pragma unroll
        for (int m = 0; m < 4; m++)
            #pragma unroll
            for (int i = 0; i < 4; i++) {
                int r = rowbase + wr * 64 + m * 16 + g4 * 4 + i;
                denom_part[(size_t)r * NPART + part] = pd[m][i];
            }
    }
}

// ---------------- Kernel C: per-row loss (one wave per row) -----------------
__global__ void rowloss_kernel(const ushort* __restrict__ fb,
                               const int* __restrict__ labels,
                               const float* __restrict__ denom_part,
                               const float* __restrict__ sq,
                               const float* __restrict__ g,
                               const float* __restrict__ cntf,
                               float* __restrict__ rowloss,
                               int N) {
    int r    = (blockIdx.x * blockDim.x + threadIdx.x) >> 6;
    int lane = threadIdx.x & 63;
    if (r >= N) return;
    int lab = labels[r];
    unsigned int pk = *reinterpret_cast<const unsigned int*>(fb + (size_t)r * KD + lane * 2);
    float f0 = bf2f((ushort)(pk & 0xffff));
    float f1 = bf2f((ushort)(pk >> 16));
    const float2 gv = *reinterpret_cast<const float2*>(g + lab * KD + lane * 2);
    float p = f0 * gv.x + f1 * gv.y;          // p_s = C_EXP*(f.g)
    #pragma unroll
    for (int off = 1; off < 64; off <<= 1) p += __shfl_xor(p, off);

    float dsum = (lane < NPART) ? denom_part[(size_t)r * NPART + lane] : 0.f;
    #pragma unroll
    for (int off = 1; off < NPART; off <<= 1) dsum += __shfl_xor(dsum, off);

    if (lane == 0) {
        float sqr    = sq[r];
        float possum = (p - sqr) * M_LN2F;
        float cnt    = cntf[lab] - 1.0f;
        float dn     = dsum - __builtin_amdgcn_exp2f(sqr);  // remove diagonal
        rowloss[r]   = -(possum - cnt * logf(dn + EPS)) / (cnt + EPS);
    }
}

// ---------------- Kernel D: mean (deterministic single-block reduce) --------
__global__ void reduce_kernel(const float* __restrict__ rowloss,
                              float* __restrict__ out, int N) {
    __shared__ float sdata[16];
    float s = 0.f;
    for (int r = threadIdx.x; r < N; r += blockDim.x) s += rowloss[r];
    #pragma unroll
    for (int off = 1; off < 64; off <<= 1) s += __shfl_xor(s, off);
    int wv = threadIdx.x >> 6;
    if ((threadIdx.x & 63) == 0) sdata[wv] = s;
    __syncthreads();
    if (threadIdx.x == 0) {
        float t = 0.f;
        int nw = (int)(blockDim.x >> 6);
        for (int i = 0; i < nw; i++) t += sdata[i];
        out[0] = t / (float)N;
    }
}

extern "C" void kernel_launch(void* const* d_in, const int* in_sizes, int n_in,
                              void* d_out, int out_size, void* d_ws, size_t ws_size,
                              hipStream_t stream) {
    const float* feat = (const float*)d_in[0];
    const int* labels = (const int*)d_in[1];
    const int N = in_sizes[1];

    char* ws = (char*)d_ws;
    size_t off = 0;
    ushort* fb = (ushort*)(ws + off);                 off += (size_t)N * KD * sizeof(ushort);
    // zeroed-by-normalize region: g[16*128], cntf[16] (contiguous)
    float* g     = (float*)(ws + off);                off += (size_t)NUM_CLASSES * KD * sizeof(float);
    float* cntf  = (float*)(ws + off);                off += (size_t)NUM_CLASSES * sizeof(float);
    // written-unconditionally: sq[N], denom_part[N*32], rowloss[N]
    float* sq         = (float*)(ws + off);           off += (size_t)N * sizeof(float);
    float* denom_part = (float*)(ws + off);           off += (size_t)N * NPART * sizeof(float);
    float* rowloss    = (float*)(ws + off);

    normalize_kernel<<<(N + 3) / 4, 256, 0, stream>>>(feat, fb, sq, g, N);
    classsum_kernel<<<CS_BLOCKS, 256, 0, stream>>>(fb, labels, g, cntf, N);

    dim3 grid(NCOLG, N / BM);                         // (8, 64) = 512 blocks
    supcon_denom<<<grid, 512, 0, stream>>>(fb, denom_part, N);

    rowloss_kernel<<<(N + 3) / 4, 256, 0, stream>>>(fb, labels, denom_part, sq, g, cntf, rowloss, N);
    reduce_kernel<<<1, 1024, 0, stream>>>(rowloss, (float*)d_out, N);
}

// Round 14
// 48.736 us; speedup vs baseline: 1.0395x; 1.0395x over previous
//
#include <hip/hip_runtime.h>
#include <hip/hip_bf16.h>

#define EPS 1e-12f
// Features stored pre-scaled by sqrt(C_EXP), C_EXP=(1/0.07)*log2(e):
// MFMA output acc = C_EXP*(f_i.f_j) is exp2-ready; possum = (pp-sq_s)*ln2.
#define SQRT_C_EXP 4.53981597f
#define M_LN2F 0.69314718056f
#define NUM_CLASSES 16

#define BM 256          // rows per denom block
#define BN 128          // cols per chunk
#define KD 128          // feature dim
#define NCHUNK 8        // col chunks per colgroup (1024 cols)
#define NPART 16        // partial slots per row per quantity
#define PSTRIDE 48      // 16 expsum + 16 possum + 16 count

typedef __attribute__((ext_vector_type(4))) float f32x4;
typedef __attribute__((ext_vector_type(8))) short bf16x8;

__device__ __forceinline__ float bf2f(ushort u) {
    unsigned int x = ((unsigned int)u) << 16;
    return __uint_as_float(x);
}

// Swizzled LDS fragment address: element (r, slot) of a [rows][128] bf16 tile,
// slot = 16B chunk within the 256B row. Swizzle: slot ^= (r&7).
__device__ __forceinline__ const bf16x8* lds_frag(const ushort* base, int r, int slot) {
    int sw = slot ^ (r & 7);
    return reinterpret_cast<const bf16x8*>(
        reinterpret_cast<const char*>(base) + r * 256 + sw * 16);
}

// ---------------- Kernel A: L2-normalize rows -> bf16 (pre-scaled) ----------
// One wave per row; D=128 = 64 lanes x float2. sq[r] = ||fs_bf16||^2 (scaled).
__global__ void normalize_kernel(const float* __restrict__ feat,
                                 ushort* __restrict__ fb,
                                 float* __restrict__ sq,
                                 int N) {
    int r    = (blockIdx.x * blockDim.x + threadIdx.x) >> 6;
    int lane = threadIdx.x & 63;
    if (r >= N) return;
    const float2 v = *reinterpret_cast<const float2*>(feat + (size_t)r * KD + lane * 2);
    float s = v.x * v.x + v.y * v.y;
    #pragma unroll
    for (int off = 1; off < 64; off <<= 1) s += __shfl_xor(s, off);
    const float scale = SQRT_C_EXP / fmaxf(sqrtf(s), EPS);

    __hip_bfloat16 h0 = __float2bfloat16(v.x * scale);
    __hip_bfloat16 h1 = __float2bfloat16(v.y * scale);
    ushort u0 = *reinterpret_cast<ushort*>(&h0);
    ushort u1 = *reinterpret_cast<ushort*>(&h1);
    unsigned int pack = (unsigned int)u0 | ((unsigned int)u1 << 16);
    *reinterpret_cast<unsigned int*>(fb + (size_t)r * KD + lane * 2) = pack;

    float q0 = bf2f(u0), q1 = bf2f(u1);
    float q = q0 * q0 + q1 * q1;
    #pragma unroll
    for (int off = 1; off < 64; off <<= 1) q += __shfl_xor(q, off);
    if (lane == 0) sq[r] = q;                 // sq_s = C_EXP*||f||^2
}

// ---------------- Kernel B: fused denom/possum/count partials ---------------
// r12 geometry: 256 blocks (8 colgroups x 32 rowblocks), 512 thr = 8 waves
// (4x2), wave tile 64x64, A-frags in registers, double-buffered B, XOR LDS.
// Epilogue per element: pd += exp2(acc); match = (rlab==clab);
// pp += match?acc:0; pc += match?1:0.  Partials: part[r][48].
__global__ __launch_bounds__(512, 2) void supcon_denom(
    const ushort* __restrict__ fb,
    const int* __restrict__ labels,
    float* __restrict__ part,
    int N) {

    __shared__ __align__(16) ushort As[BM * KD];        // 64 KB
    __shared__ __align__(16) ushort Bs[2][BN * KD];     // 2 x 32 KB

    const int tid  = threadIdx.x;
    const int lane = tid & 63;
    const int w    = tid >> 6;        // 0..7
    const int wr   = w >> 1;          // 0..3  (64-row quadrant)
    const int wc   = w & 1;           // 0..1  (64-col half)
    const int r16  = lane & 15;
    const int g4   = lane >> 4;       // 0..3

    const int rowbase = blockIdx.y * BM;
    const int col0    = blockIdx.x * (BN * NCHUNK);

    // ---- stage A tile (64KB) + B chunk 0 (32KB) ----
    {
        const ushort* gA = fb + (size_t)rowbase * KD;
        #pragma unroll
        for (int i = 0; i < 8; i++) {
            int c = i * 512 + tid;                  // 16B chunk index
            bf16x8 v = *reinterpret_cast<const bf16x8*>(gA + c * 8);
            int dst = c ^ ((c >> 4) & 7);
            *reinterpret_cast<bf16x8*>(&As[dst * 8]) = v;
        }
        const ushort* gB = fb + (size_t)col0 * KD;
        #pragma unroll
        for (int i = 0; i < 4; i++) {
            int c = i * 512 + tid;
            bf16x8 v = *reinterpret_cast<const bf16x8*>(gB + c * 8);
            int dst = c ^ ((c >> 4) & 7);
            *reinterpret_cast<bf16x8*>(&Bs[0][dst * 8]) = v;
        }
    }

    // row labels for this lane's 16 output rows (L2-hot)
    int rlab[4][4];
    #pragma unroll
    for (int m = 0; m < 4; m++)
        #pragma unroll
        for (int i = 0; i < 4; i++)
            rlab[m][i] = labels[rowbase + wr * 64 + m * 16 + g4 * 4 + i];

    __syncthreads();

    // ---- A fragments for the whole block, read from LDS once ----
    bf16x8 a[4][4];                   // [ks][m], 64 VGPR, static indexing only
    #pragma unroll
    for (int ks = 0; ks < 4; ks++) {
        const int slot = ks * 4 + g4;
        #pragma unroll
        for (int m = 0; m < 4; m++)
            a[ks][m] = *lds_frag(As, wr * 64 + m * 16 + r16, slot);
    }

    float pd[4][4], pp[4][4], pc[4][4];
    #pragma unroll
    for (int m = 0; m < 4; m++)
        #pragma unroll
        for (int i = 0; i < 4; i++) { pd[m][i] = 0.f; pp[m][i] = 0.f; pc[m][i] = 0.f; }

    int cur = 0;
    for (int c = 0; c < NCHUNK; c++) {
        // issue next-chunk global loads early (latency hides under MFMA+exp)
        bf16x8 pre0, pre1, pre2, pre3;
        if (c + 1 < NCHUNK) {
            const ushort* gB = fb + (size_t)(col0 + (c + 1) * BN) * KD;
            pre0 = *reinterpret_cast<const bf16x8*>(gB + (0 * 512 + tid) * 8);
            pre1 = *reinterpret_cast<const bf16x8*>(gB + (1 * 512 + tid) * 8);
            pre2 = *reinterpret_cast<const bf16x8*>(gB + (2 * 512 + tid) * 8);
            pre3 = *reinterpret_cast<const bf16x8*>(gB + (3 * 512 + tid) * 8);
        }
        // column labels for this chunk (4 per lane, L2-hot)
        const int colbase = col0 + c * BN + wc * 64;
        int clab[4];
        #pragma unroll
        for (int n = 0; n < 4; n++)
            clab[n] = labels[colbase + n * 16 + r16];

        f32x4 acc[4][4];
        #pragma unroll
        for (int m = 0; m < 4; m++)
            #pragma unroll
            for (int n = 0; n < 4; n++) acc[m][n] = f32x4{0.f, 0.f, 0.f, 0.f};

        const ushort* bbase = Bs[cur];
        #pragma unroll
        for (int ks = 0; ks < 4; ks++) {
            const int slot = ks * 4 + g4;
            bf16x8 bv[4];
            #pragma unroll
            for (int n = 0; n < 4; n++)
                bv[n] = *lds_frag(bbase, wc * 64 + n * 16 + r16, slot);
            #pragma unroll
            for (int m = 0; m < 4; m++)
                #pragma unroll
                for (int n = 0; n < 4; n++)
                    acc[m][n] = __builtin_amdgcn_mfma_f32_16x16x32_bf16(a[ks][m], bv[n], acc[m][n], 0, 0, 0);
        }

        #pragma unroll
        for (int m = 0; m < 4; m++)
            #pragma unroll
            for (int n = 0; n < 4; n++)
                #pragma unroll
                for (int i = 0; i < 4; i++) {
                    const float sim = acc[m][n][i];
                    pd[m][i] += __builtin_amdgcn_exp2f(sim);
                    const bool mt = (rlab[m][i] == clab[n]);
                    pp[m][i] += mt ? sim : 0.f;
                    pc[m][i] += mt ? 1.f : 0.f;
                }

        if (c + 1 < NCHUNK) {
            ushort* dstb = Bs[cur ^ 1];
            int ch;
            ch = 0 * 512 + tid; *reinterpret_cast<bf16x8*>(&dstb[(ch ^ ((ch >> 4) & 7)) * 8]) = pre0;
            ch = 1 * 512 + tid; *reinterpret_cast<bf16x8*>(&dstb[(ch ^ ((ch >> 4) & 7)) * 8]) = pre1;
            ch = 2 * 512 + tid; *reinterpret_cast<bf16x8*>(&dstb[(ch ^ ((ch >> 4) & 7)) * 8]) = pre2;
            ch = 3 * 512 + tid; *reinterpret_cast<bf16x8*>(&dstb[(ch ^ ((ch >> 4) & 7)) * 8]) = pre3;
        }
        __syncthreads();
        cur ^= 1;
    }

    // reduce across the 16 lanes sharing the same rows, write 3 partials
    #pragma unroll
    for (int off = 1; off < 16; off <<= 1)
        #pragma unroll
        for (int m = 0; m < 4; m++)
            #pragma unroll
            for (int i = 0; i < 4; i++) {
                pd[m][i] += __shfl_xor(pd[m][i], off);
                pp[m][i] += __shfl_xor(pp[m][i], off);
                pc[m][i] += __shfl_xor(pc[m][i], off);
            }

    if (r16 == 0) {
        const int slot = blockIdx.x * 2 + wc;   // 0..15
        #pragma unroll
        for (int m = 0; m < 4; m++)
            #pragma unroll
            for (int i = 0; i < 4; i++) {
                int r = rowbase + wr * 64 + m * 16 + g4 * 4 + i;
                float* p = part + (size_t)r * PSTRIDE + slot;
                p[0]  = pd[m][i];
                p[16] = pp[m][i];
                p[32] = pc[m][i];
            }
    }
}

// ---------------- Kernel C: per-row loss (one wave per row) -----------------
// Reads only part[r][48] + sq[r]: lanes 0-15 expsum, 16-31 possum, 32-47 cnt.
__global__ void rowloss_kernel(const float* __restrict__ part,
                               const float* __restrict__ sq,
                               float* __restrict__ rowloss,
                               int N) {
    int r    = (blockIdx.x * blockDim.x + threadIdx.x) >> 6;
    int lane = threadIdx.x & 63;
    if (r >= N) return;

    float v = (lane < PSTRIDE) ? part[(size_t)r * PSTRIDE + lane] : 0.f;
    #pragma unroll
    for (int off = 1; off < 16; off <<= 1) v += __shfl_xor(v, off);
    float dsum = __shfl(v, 0);
    float psum = __shfl(v, 16);
    float csum = __shfl(v, 32);

    if (lane == 0) {
        float sqr    = sq[r];
        float possum = (psum - sqr) * M_LN2F;
        float cnt    = csum - 1.0f;
        float dn     = dsum - __builtin_amdgcn_exp2f(sqr);  // remove diagonal
        rowloss[r]   = -(possum - cnt * logf(dn + EPS)) / (cnt + EPS);
    }
}

// ---------------- Kernel D: mean (deterministic single-block reduce) --------
__global__ void reduce_kernel(const float* __restrict__ rowloss,
                              float* __restrict__ out, int N) {
    __shared__ float sdata[16];
    float s = 0.f;
    for (int r = threadIdx.x; r < N; r += blockDim.x) s += rowloss[r];
    #pragma unroll
    for (int off = 1; off < 64; off <<= 1) s += __shfl_xor(s, off);
    int wv = threadIdx.x >> 6;
    if ((threadIdx.x & 63) == 0) sdata[wv] = s;
    __syncthreads();
    if (threadIdx.x == 0) {
        float t = 0.f;
        int nw = (int)(blockDim.x >> 6);
        for (int i = 0; i < nw; i++) t += sdata[i];
        out[0] = t / (float)N;
    }
}

extern "C" void kernel_launch(void* const* d_in, const int* in_sizes, int n_in,
                              void* d_out, int out_size, void* d_ws, size_t ws_size,
                              hipStream_t stream) {
    const float* feat = (const float*)d_in[0];
    const int* labels = (const int*)d_in[1];
    const int N = in_sizes[1];

    char* ws = (char*)d_ws;
    size_t off = 0;
    ushort* fb     = (ushort*)(ws + off);  off += (size_t)N * KD * sizeof(ushort);
    float* sq      = (float*)(ws + off);   off += (size_t)N * sizeof(float);
    float* part    = (float*)(ws + off);   off += (size_t)N * PSTRIDE * sizeof(float);
    float* rowloss = (float*)(ws + off);

    normalize_kernel<<<(N + 3) / 4, 256, 0, stream>>>(feat, fb, sq, N);

    dim3 grid(N / (BN * NCHUNK), N / BM);             // (8, 32) = 256 blocks
    supcon_denom<<<grid, 512, 0, stream>>>(fb, labels, part, N);

    rowloss_kernel<<<(N + 3) / 4, 256, 0, stream>>>(part, sq, rowloss, N);
    reduce_kernel<<<1, 1024, 0, stream>>>(rowloss, (float*)d_out, N);
}

// Round 15
// 48.628 us; speedup vs baseline: 1.0419x; 1.0022x over previous
//
#include <hip/hip_runtime.h>
#include <hip/hip_bf16.h>

#define EPS 1e-12f
// Features stored pre-scaled by sqrt(C_EXP), C_EXP=(1/0.07)*log2(e):
// MFMA output acc = C_EXP*(f_i.f_j) is exp2-ready; possum = (pp-sq_s)*ln2.
#define SQRT_C_EXP 4.53981597f
#define M_LN2F 0.69314718056f

#define BM 256          // rows per denom block
#define BN 128          // cols per chunk
#define KD 128          // feature dim
#define NCHUNK 8        // col chunks per colgroup (1024 cols)
#define NPART 16        // partial slots per row per quantity
#define PSTRIDE 48      // 16 expsum + 16 possum + 16 count

typedef __attribute__((ext_vector_type(4))) float f32x4;
typedef __attribute__((ext_vector_type(8))) short bf16x8;

__device__ __forceinline__ float bf2f(ushort u) {
    unsigned int x = ((unsigned int)u) << 16;
    return __uint_as_float(x);
}

// Direct global->LDS 16B/lane DMA. LDS dest is linear in lane order; the XOR
// swizzle is pre-applied to the GLOBAL source address (involution), so the
// resulting LDS layout equals the swizzled layout lds_frag expects.
__device__ __forceinline__ void gload16(const void* g, void* l) {
    __builtin_amdgcn_global_load_lds(
        (const __attribute__((address_space(1))) void*)g,
        (__attribute__((address_space(3))) void*)l, 16, 0, 0);
}

// Swizzled LDS fragment address: element (r, slot) of a [rows][128] bf16 tile,
// slot = 16B chunk within the 256B row. Swizzle: slot ^= (r&7).
__device__ __forceinline__ const bf16x8* lds_frag(const ushort* base, int r, int slot) {
    int sw = slot ^ (r & 7);
    return reinterpret_cast<const bf16x8*>(
        reinterpret_cast<const char*>(base) + r * 256 + sw * 16);
}

// ---------------- Kernel A: L2-normalize rows -> bf16 (pre-scaled) ----------
// One wave per row; D=128 = 64 lanes x float2. sq[r] = ||fs_bf16||^2 (scaled).
__global__ void normalize_kernel(const float* __restrict__ feat,
                                 ushort* __restrict__ fb,
                                 float* __restrict__ sq,
                                 int N) {
    int r    = (blockIdx.x * blockDim.x + threadIdx.x) >> 6;
    int lane = threadIdx.x & 63;
    if (r >= N) return;
    const float2 v = *reinterpret_cast<const float2*>(feat + (size_t)r * KD + lane * 2);
    float s = v.x * v.x + v.y * v.y;
    #pragma unroll
    for (int off = 1; off < 64; off <<= 1) s += __shfl_xor(s, off);
    const float scale = SQRT_C_EXP / fmaxf(sqrtf(s), EPS);

    __hip_bfloat16 h0 = __float2bfloat16(v.x * scale);
    __hip_bfloat16 h1 = __float2bfloat16(v.y * scale);
    ushort u0 = *reinterpret_cast<ushort*>(&h0);
    ushort u1 = *reinterpret_cast<ushort*>(&h1);
    unsigned int pack = (unsigned int)u0 | ((unsigned int)u1 << 16);
    *reinterpret_cast<unsigned int*>(fb + (size_t)r * KD + lane * 2) = pack;

    float q0 = bf2f(u0), q1 = bf2f(u1);
    float q = q0 * q0 + q1 * q1;
    #pragma unroll
    for (int off = 1; off < 64; off <<= 1) q += __shfl_xor(q, off);
    if (lane == 0) sq[r] = q;                 // sq_s = C_EXP*||f||^2
}

// ---------------- Kernel B: fused denom/possum/count partials ---------------
// 256 blocks (8 colgroups x 32 rowblocks), 512 thr = 8 waves (4x2), wave tile
// 64x64. A-frags in registers (64 VGPR). Staging via global_load_lds (no
// staging VGPRs). n-loop NOT unrolled: only acc[4] (16 regs) live at a time.
// Epilogue: pd += exp2(acc); mt=(rlab==clab); pp += mt?acc:0; pc += mt?1:0.
__global__ __launch_bounds__(512, 2) void supcon_denom(
    const ushort* __restrict__ fb,
    const int* __restrict__ labels,
    float* __restrict__ part,
    int N) {

    __shared__ __align__(16) ushort As[BM * KD];        // 64 KB
    __shared__ __align__(16) ushort Bs[2][BN * KD];     // 2 x 32 KB

    const int tid  = threadIdx.x;
    const int lane = tid & 63;
    const int w    = tid >> 6;        // 0..7
    const int wr   = w >> 1;          // 0..3  (64-row quadrant)
    const int wc   = w & 1;           // 0..1  (64-col half)
    const int r16  = lane & 15;
    const int g4   = lane >> 4;       // 0..3

    const int rowbase = blockIdx.y * BM;
    const int col0    = blockIdx.x * (BN * NCHUNK);

    // ---- stage A tile (64KB = 8 DMA) + B chunk 0 (32KB = 4 DMA) ----
    {
        const ushort* gA = fb + (size_t)rowbase * KD;
        #pragma unroll
        for (int i = 0; i < 8; i++) {
            int d = i * 512 + tid;                  // linear 16B-chunk index
            int s = d ^ ((d >> 4) & 7);             // pre-swizzled source
            gload16(gA + (size_t)s * 8, &As[d * 8]);
        }
        const ushort* gB = fb + (size_t)col0 * KD;
        #pragma unroll
        for (int i = 0; i < 4; i++) {
            int d = i * 512 + tid;
            int s = d ^ ((d >> 4) & 7);
            gload16(gB + (size_t)s * 8, &Bs[0][d * 8]);
        }
    }

    // row labels for this lane's 16 output rows (L2-hot, loads overlap DMA)
    int rlab[4][4];
    #pragma unroll
    for (int m = 0; m < 4; m++)
        #pragma unroll
        for (int i = 0; i < 4; i++)
            rlab[m][i] = labels[rowbase + wr * 64 + m * 16 + g4 * 4 + i];

    __syncthreads();

    // ---- A fragments for the whole block, read from LDS once ----
    bf16x8 a[4][4];                   // [ks][m], 64 VGPR, static indexing only
    #pragma unroll
    for (int ks = 0; ks < 4; ks++) {
        const int slot = ks * 4 + g4;
        #pragma unroll
        for (int m = 0; m < 4; m++)
            a[ks][m] = *lds_frag(As, wr * 64 + m * 16 + r16, slot);
    }

    float pd[4][4], pp[4][4], pc[4][4];
    #pragma unroll
    for (int m = 0; m < 4; m++)
        #pragma unroll
        for (int i = 0; i < 4; i++) { pd[m][i] = 0.f; pp[m][i] = 0.f; pc[m][i] = 0.f; }

    int cur = 0;
    for (int c = 0; c < NCHUNK; c++) {
        // issue next-chunk DMA into the other buffer (drained by the barrier)
        if (c + 1 < NCHUNK) {
            const ushort* gB = fb + (size_t)(col0 + (c + 1) * BN) * KD;
            ushort* dstb = Bs[cur ^ 1];
            #pragma unroll
            for (int i = 0; i < 4; i++) {
                int d = i * 512 + tid;
                int s = d ^ ((d >> 4) & 7);
                gload16(gB + (size_t)s * 8, &dstb[d * 8]);
            }
        }

        const ushort* bbase = Bs[cur];
        const int colbase = col0 + c * BN + wc * 64;

        #pragma unroll 1                       // keep ONE acc[4] live
        for (int n = 0; n < 4; n++) {
            const int clab = labels[colbase + n * 16 + r16];  // L1-hot scalar

            f32x4 acc[4];
            #pragma unroll
            for (int m = 0; m < 4; m++) acc[m] = f32x4{0.f, 0.f, 0.f, 0.f};

            #pragma unroll
            for (int ks = 0; ks < 4; ks++) {
                const int slot = ks * 4 + g4;
                bf16x8 bv = *lds_frag(bbase, wc * 64 + n * 16 + r16, slot);
                #pragma unroll
                for (int m = 0; m < 4; m++)
                    acc[m] = __builtin_amdgcn_mfma_f32_16x16x32_bf16(a[ks][m], bv, acc[m], 0, 0, 0);
            }

            #pragma unroll
            for (int m = 0; m < 4; m++)
                #pragma unroll
                for (int i = 0; i < 4; i++) {
                    const float sim = acc[m][i];
                    pd[m][i] += __builtin_amdgcn_exp2f(sim);
                    const bool mt = (rlab[m][i] == clab);
                    pp[m][i] += mt ? sim : 0.f;
                    pc[m][i] += mt ? 1.f : 0.f;
                }
        }

        __syncthreads();
        cur ^= 1;
    }

    // reduce across the 16 lanes sharing the same rows, write 3 partials
    #pragma unroll
    for (int off = 1; off < 16; off <<= 1)
        #pragma unroll
        for (int m = 0; m < 4; m++)
            #pragma unroll
            for (int i = 0; i < 4; i++) {
                pd[m][i] += __shfl_xor(pd[m][i], off);
                pp[m][i] += __shfl_xor(pp[m][i], off);
                pc[m][i] += __shfl_xor(pc[m][i], off);
            }

    if (r16 == 0) {
        const int slot = blockIdx.x * 2 + wc;   // 0..15
        #pragma unroll
        for (int m = 0; m < 4; m++)
            #pragma unroll
            for (int i = 0; i < 4; i++) {
                int r = rowbase + wr * 64 + m * 16 + g4 * 4 + i;
                float* p = part + (size_t)r * PSTRIDE + slot;
                p[0]  = pd[m][i];
                p[16] = pp[m][i];
                p[32] = pc[m][i];
            }
    }
}

// ---------------- Kernel C: per-row loss (one wave per row) -----------------
// Reads only part[r][48] + sq[r]: lanes 0-15 expsum, 16-31 possum, 32-47 cnt.
__global__ void rowloss_kernel(const float* __restrict__ part,
                               const float* __restrict__ sq,
                               float* __restrict__ rowloss,
                               int N) {
    int r    = (blockIdx.x * blockDim.x + threadIdx.x) >> 6;
    int lane = threadIdx.x & 63;
    if (r >= N) return;

    float v = (lane < PSTRIDE) ? part[(size_t)r * PSTRIDE + lane] : 0.f;
    #pragma unroll
    for (int off = 1; off < 16; off <<= 1) v += __shfl_xor(v, off);
    float dsum = __shfl(v, 0);
    float psum = __shfl(v, 16);
    float csum = __shfl(v, 32);

    if (lane == 0) {
        float sqr    = sq[r];
        float possum = (psum - sqr) * M_LN2F;
        float cnt    = csum - 1.0f;
        float dn     = dsum - __builtin_amdgcn_exp2f(sqr);  // remove diagonal
        rowloss[r]   = -(possum - cnt * logf(dn + EPS)) / (cnt + EPS);
    }
}

// ---------------- Kernel D: mean (deterministic single-block reduce) --------
__global__ void reduce_kernel(const float* __restrict__ rowloss,
                              float* __restrict__ out, int N) {
    __shared__ float sdata[16];
    float s = 0.f;
    for (int r = threadIdx.x; r < N; r += blockDim.x) s += rowloss[r];
    #pragma unroll
    for (int off = 1; off < 64; off <<= 1) s += __shfl_xor(s, off);
    int wv = threadIdx.x >> 6;
    if ((threadIdx.x & 63) == 0) sdata[wv] = s;
    __syncthreads();
    if (threadIdx.x == 0) {
        float t = 0.f;
        int nw = (int)(blockDim.x >> 6);
        for (int i = 0; i < nw; i++) t += sdata[i];
        out[0] = t / (float)N;
    }
}

extern "C" void kernel_launch(void* const* d_in, const int* in_sizes, int n_in,
                              void* d_out, int out_size, void* d_ws, size_t ws_size,
                              hipStream_t stream) {
    const float* feat = (const float*)d_in[0];
    const int* labels = (const int*)d_in[1];
    const int N = in_sizes[1];

    char* ws = (char*)d_ws;
    size_t off = 0;
    ushort* fb     = (ushort*)(ws + off);  off += (size_t)N * KD * sizeof(ushort);
    float* sq      = (float*)(ws + off);   off += (size_t)N * sizeof(float);
    float* part    = (float*)(ws + off);   off += (size_t)N * PSTRIDE * sizeof(float);
    float* rowloss = (float*)(ws + off);

    normalize_kernel<<<(N + 3) / 4, 256, 0, stream>>>(feat, fb, sq, N);

    dim3 grid(N / (BN * NCHUNK), N / BM);             // (8, 32) = 256 blocks
    supcon_denom<<<grid, 512, 0, stream>>>(fb, labels, part, N);

    rowloss_kernel<<<(N + 3) / 4, 256, 0, stream>>>(part, sq, rowloss, N);
    reduce_kernel<<<1, 1024, 0, stream>>>(rowloss, (float*)d_out, N);
}